// Round 9
// baseline (318.244 us; speedup 1.0000x reference)
//
#include <hip/hip_runtime.h>
#include <hip/hip_bf16.h>
#include <stdint.h>

// Problem: out = x_norm + dropout(relu(LN(x) @ W1) @ W2), B=4,S=2048,D=2048
#define M_DIM 8192   // B*S
#define N_DIM 2048
#define K_DIM 2048

typedef __bf16 bf16x8_t __attribute__((ext_vector_type(8)));
typedef float f32x4_t __attribute__((ext_vector_type(4)));
typedef float f32x16_t __attribute__((ext_vector_type(16)));

// ---------------- threefry2x32, JAX partitionable path, key=(0,1) -------------
// bits(j) = o0^o1 of threefry2x32(key=(0,1), ctr=(0, j)); keep iff bits < 0xC0000000.
// Verified: absmax 0.0625 -> mask exact.
__device__ __forceinline__ unsigned tf_rotl(unsigned x, int r) {
  return (x << r) | (x >> (32 - r));
}
__device__ __forceinline__ unsigned threefry_mask_bits(unsigned ctr) {
  unsigned x0 = 0u, x1 = ctr;
  const unsigned ks0 = 0u, ks1 = 1u, ks2 = 0x1BD11BDBu;
  x0 += ks0; x1 += ks1;
#define TFR(r) { x0 += x1; x1 = tf_rotl(x1, (r)); x1 ^= x0; }
  TFR(13) TFR(15) TFR(26) TFR(6)
  x0 += ks1; x1 += ks2 + 1u;
  TFR(17) TFR(29) TFR(16) TFR(24)
  x0 += ks2; x1 += ks0 + 2u;
  TFR(13) TFR(15) TFR(26) TFR(6)
  x0 += ks0; x1 += ks1 + 3u;
  TFR(17) TFR(29) TFR(16) TFR(24)
  x0 += ks1; x1 += ks2 + 4u;
  TFR(13) TFR(15) TFR(26) TFR(6)
  x0 += ks2; x1 += ks0 + 5u;
#undef TFR
  return x0 ^ x1;
}

// ---------------- async global->LDS, 16B per lane -----------------------------
__device__ __forceinline__ void gload_lds16(const __hip_bfloat16* g, unsigned short* l) {
  __builtin_amdgcn_global_load_lds(
      (const __attribute__((address_space(1))) unsigned int*)g,
      (__attribute__((address_space(3))) unsigned int*)l,
      16, 0, 0);
}

// ---------------- merged prep: LN (blocks 0..8191) + W transpose (8192..16383)
__global__ __launch_bounds__(256) void prep_kernel(
    const float* __restrict__ X,  __hip_bfloat16* __restrict__ Xn,
    const float* __restrict__ W1, const float* __restrict__ W2,
    __hip_bfloat16* __restrict__ W1t, __hip_bfloat16* __restrict__ W2t) {
  const int bid = blockIdx.x;
  if (bid < M_DIM) {
    // ---- LayerNorm row (no affine) -> bf16
    const int row = bid;
    const float4* xv = (const float4*)(X + (size_t)row * K_DIM);
    float4 v0 = xv[threadIdx.x];
    float4 v1 = xv[threadIdx.x + 256];
    float s  = v0.x + v0.y + v0.z + v0.w + v1.x + v1.y + v1.z + v1.w;
    float ss = v0.x*v0.x + v0.y*v0.y + v0.z*v0.z + v0.w*v0.w
             + v1.x*v1.x + v1.y*v1.y + v1.z*v1.z + v1.w*v1.w;
#pragma unroll
    for (int off = 32; off > 0; off >>= 1) {
      s  += __shfl_xor(s, off);
      ss += __shfl_xor(ss, off);
    }
    __shared__ float rs[4], rss[4];
    const int wave = threadIdx.x >> 6;
    if ((threadIdx.x & 63) == 0) { rs[wave] = s; rss[wave] = ss; }
    __syncthreads();
    float S  = rs[0] + rs[1] + rs[2] + rs[3];
    float SS = rss[0] + rss[1] + rss[2] + rss[3];
    float mean = S * (1.0f / 2048.0f);
    float var  = SS * (1.0f / 2048.0f) - mean * mean;
    float rstd = 1.0f / sqrtf(var + 1e-6f);
    float vv[8] = {v0.x, v0.y, v0.z, v0.w, v1.x, v1.y, v1.z, v1.w};
    unsigned short o[8];
#pragma unroll
    for (int i = 0; i < 8; i++) {
      __hip_bfloat16 b = __float2bfloat16((vv[i] - mean) * rstd);
      o[i] = *(unsigned short*)&b;
    }
    ushort4* dst = (ushort4*)(Xn + (size_t)row * K_DIM);
    dst[threadIdx.x]       = make_ushort4(o[0], o[1], o[2], o[3]);
    dst[threadIdx.x + 256] = make_ushort4(o[4], o[5], o[6], o[7]);
  } else {
    // ---- W [K][N] fp32 -> Wt [N][K] bf16, 32x32 tile
    const int t = bid - M_DIM;
    const int z  = t >> 12;           // 0: W1, 1: W2  (4096 tiles each)
    const int r  = t & 4095;
    const int bx = r & 63;
    const int by = r >> 6;
    const int tx = threadIdx.x & 31;
    const int ty = threadIdx.x >> 5;  // 0..7
    __shared__ float tile[32][33];
    const float* src = z ? W2 : W1;
    __hip_bfloat16* dst = z ? W2t : W1t;
    int x = bx * 32 + tx;
    int y = by * 32 + ty;
#pragma unroll
    for (int i = 0; i < 32; i += 8)
      tile[ty + i][tx] = src[(size_t)(y + i) * N_DIM + x];
    __syncthreads();
    int xo = by * 32 + tx;
    int yo = bx * 32 + ty;
#pragma unroll
    for (int i = 0; i < 32; i += 8)
      dst[(size_t)(yo + i) * K_DIM + xo] = __float2bfloat16(tile[tx][ty + i]);
  }
}

// ---------------- 128x128 MFMA GEMM, BK=64 dbuf, counted vmcnt, 8 waves -------
// Round-8 post-mortem: MfmaUtil (28%) == ideal-MFMA-time/dur; nothing
// saturated; occupancy 20% (2 waves/SIMD) -> latency-bound with no cross-wave
// cover. This round: same 128x128/BK=64 tile, same counted-vmcnt dbuf skeleton
// and 32x32x16 MFMA, but 512-thread blocks (8 waves, 2Mx4N split, per-wave
// 64x32 out). acc = 2 x f32x16 = 32 AGPR (named, no dynamic idx). launch_
// bounds(512,4) caps regs at 128/wave -> 2 blocks/CU x 8 waves = 16 waves/CU
// (40% occupancy, 2x round 8). LDS 64KB unchanged; staging 4 gloads/thread
// (16 x 1KB chunks over 8 waves); per-tile wait VMW(4). Accumulation order
// per output element identical to round 8 (ks=0..3 per K-64 tile, tiles
// sequential) -> identical numerics.
// Pipeline per tile t (buf=t&1): COMPUTE(buf); s_barrier; STAGE(buf, t+2);
// vmcnt(4); s_barrier. Drain vmcnt(0) only at tile 30; tile 31 computes only.
// C/D layout (m74/m101): col = lane&31, row = (reg&3)+8*(reg>>2)+4*(lane>>5).
// EPI=0: H=relu(A@B)->bf16. EPI=1: out=Xn+dropout/0.75.
template <int EPI>
__global__ __launch_bounds__(512, 4) void gemm128(
    const __hip_bfloat16* __restrict__ A,
    const __hip_bfloat16* __restrict__ Bt,
    const __hip_bfloat16* __restrict__ Xn,   // EPI=1 residual
    __hip_bfloat16* __restrict__ Hout,       // EPI=0 output
    float* __restrict__ Fout) {              // EPI=1 output
  __shared__ unsigned short As[2][128 * 64];  // 32 KB
  __shared__ unsigned short Bs[2][128 * 64];  // 32 KB
  const int tid  = threadIdx.x;
  const int lane = tid & 63;
  const int wave = tid >> 6;      // 0..7
  const int wm = wave >> 2;       // 0..1: 64-row half
  const int wn = wave & 3;        // 0..3: 32-col quarter
  // grid: x walks M (fastest) -> consecutive blocks share the B panel in L2.
  const int mBase = blockIdx.x * 128;
  const int nBase = blockIdx.y * 128;

  f32x16_t acc0, acc1;
#pragma unroll
  for (int e = 0; e < 16; e++) { acc0[e] = 0.0f; acc1[e] = 0.0f; }

  // ---- staging: 16 KB per matrix per stage = 16 chunks of 1 KB (8 rows x 128B).
  // 8 waves: wave w loads chunks {w, w+8} of A and of B (4 gloads/thread).
  // lane l covers row 8*ca + (l>>3), source k-chunk (l&7)^((l>>3)&7) (swizzle).
  const int rowIn  = lane >> 3;                       // 0..7 within chunk
  const int csrc   = ((lane & 7) ^ (rowIn & 7)) << 3; // swizzled src k-elem offset
  const __hip_bfloat16* aSrc[2];
  const __hip_bfloat16* bSrc[2];
  int sDst[2];
#pragma unroll
  for (int j = 0; j < 2; j++) {
    const int ca = wave + 8 * j;                      // chunk index 0..15
    aSrc[j] = A  + (size_t)(mBase + 8 * ca + rowIn) * K_DIM + csrc;
    bSrc[j] = Bt + (size_t)(nBase + 8 * ca + rowIn) * K_DIM + csrc;
    sDst[j] = ca * 512;                               // shorts: 1KB per chunk
  }

  // ---- fragment read addresses for 32x32x16 (slot = chunk ^ (row&7))
  const int r32 = lane & 31;            // row/col within 32-tile
  const int kg  = lane >> 5;            // 0/1: which 8-elem k-group
  const int sw  = r32 & 7;              // row&7 (wm*64, wn*32, +32 are 0 mod 8)
  const int rowA = (wm * 64 + r32) * 64;    // mt=0 base (mt=1 at +32*64 shorts)
  const int rowB = (wn * 32 + r32) * 64;

#define STAGE(buf, k0)                                        \
  {                                                           \
    _Pragma("unroll")                                         \
    for (int j = 0; j < 2; j++) {                             \
      gload_lds16(aSrc[j] + (k0), &As[buf][sDst[j]]);         \
      gload_lds16(bSrc[j] + (k0), &Bs[buf][sDst[j]]);         \
    }                                                         \
  }

  // per k-slice ks (K=16): chunk = 2*ks + kg, slot = chunk^sw, shorts <<3
#define COMPUTE(buf)                                                            \
  {                                                                             \
    _Pragma("unroll")                                                           \
    for (int ks = 0; ks < 4; ks++) {                                            \
      const int ck = (((ks << 1) | kg) ^ sw) << 3;                              \
      bf16x8_t a0 = *(const bf16x8_t*)(&As[buf][rowA + ck]);                    \
      bf16x8_t a1 = *(const bf16x8_t*)(&As[buf][rowA + 2048 + ck]);             \
      bf16x8_t b  = *(const bf16x8_t*)(&Bs[buf][rowB + ck]);                    \
      acc0 = __builtin_amdgcn_mfma_f32_32x32x16_bf16(a0, b, acc0, 0, 0, 0);     \
      acc1 = __builtin_amdgcn_mfma_f32_32x32x16_bf16(a1, b, acc1, 0, 0, 0);     \
    }                                                                           \
  }

#define BAR() __builtin_amdgcn_s_barrier()
#define VMW(n)  asm volatile("s_waitcnt vmcnt(" #n ")" ::: "memory")

  // TSTEP(BUF, STG, KNEXT, VMODE): one K-64 tile on buffer BUF (literal).
  // STG: stage tile t+2 at offset KNEXT into BUF. VMODE 0 = VMW(4) counted,
  // 1 = VMW(0) drain (tile 30), 2 = none (tile 31).
#define TSTEP(BUF, STG, KNEXT, VMODE)                                    \
  {                                                                      \
    COMPUTE(BUF)                                                         \
    BAR();                        /* all waves done reading BUF */       \
    if (STG) { STAGE(BUF, KNEXT) }                                       \
    if ((VMODE) == 0) { VMW(4); } else if ((VMODE) == 1) { VMW(0); }     \
    if ((VMODE) != 2) { BAR(); }  /* next buffer published */            \
  }

  // ---- prologue: tiles 0 and 1 staged; VMW(4) -> tile0's 4 gloads landed.
  STAGE(0, 0)
  STAGE(1, 64)
  VMW(4);
  BAR();

  // 32 K-tiles. Pairs (t, t+1) with literal buffers; tile t stages t+2.
  for (int k0 = 0; k0 < 1920; k0 += 128) {
    TSTEP(0, 1, k0 + 128, 0)
    TSTEP(1, 1, k0 + 192, 0)
  }
  TSTEP(0, 0, 0, 1)
  TSTEP(1, 0, 0, 2)

#undef TSTEP
#undef STAGE
#undef COMPUTE
#undef BAR
#undef VMW

  // epilogue: 32x32 C/D layout: col = r32, row = (r&3) + 8*(r>>2) + 4*kg
  const int col = nBase + wn * 32 + r32;
  const int mRow = mBase + wm * 64;
#pragma unroll
  for (int mt = 0; mt < 2; mt++) {
#pragma unroll
    for (int r = 0; r < 16; r++) {
      const int row = mRow + mt * 32 + (r & 3) + ((r >> 2) << 3) + (kg << 2);
      float v = mt ? acc1[r] : acc0[r];
      size_t j = (size_t)row * N_DIM + col;
      if (EPI == 0) {
        Hout[j] = __float2bfloat16(fmaxf(v, 0.0f));
      } else {
        unsigned bits = threefry_mask_bits((unsigned)j);
        float y  = (bits < 0xC0000000u) ? v * (1.0f / 0.75f) : 0.0f;
        Fout[j]  = __bfloat162float(Xn[j]) + y;
      }
    }
  }
}

extern "C" void kernel_launch(void* const* d_in, const int* in_sizes, int n_in,
                              void* d_out, int out_size, void* d_ws, size_t ws_size,
                              hipStream_t stream) {
  (void)in_sizes; (void)n_in; (void)out_size; (void)ws_size;
  const float* X  = (const float*)d_in[0];
  const float* W1 = (const float*)d_in[1];
  const float* W2 = (const float*)d_in[2];
  float* out = (float*)d_out;

  unsigned char* ws = (unsigned char*)d_ws;
  __hip_bfloat16* Xn  = (__hip_bfloat16*)(ws);                       // 32 MB
  __hip_bfloat16* H   = (__hip_bfloat16*)(ws + ((size_t)32 << 20));  // 32 MB
  __hip_bfloat16* W1t = (__hip_bfloat16*)(ws + ((size_t)64 << 20));  //  8 MB
  __hip_bfloat16* W2t = (__hip_bfloat16*)(ws + ((size_t)72 << 20));  //  8 MB

  prep_kernel<<<dim3(2 * M_DIM, 1, 1), 256, 0, stream>>>(X, Xn, W1, W2, W1t, W2t);
  gemm128<0><<<dim3(M_DIM / 128, N_DIM / 128), dim3(512, 1, 1), 0, stream>>>(Xn, W1t, nullptr, H, nullptr);
  gemm128<1><<<dim3(M_DIM / 128, N_DIM / 128), dim3(512, 1, 1), 0, stream>>>(H, W2t, Xn, nullptr, out);
}

// Round 10
// 313.036 us; speedup vs baseline: 1.0166x; 1.0166x over previous
//
#include <hip/hip_runtime.h>
#include <hip/hip_bf16.h>
#include <stdint.h>

// Problem: out = x_norm + dropout(relu(LN(x) @ W1) @ W2), B=4,S=2048,D=2048
#define M_DIM 8192   // B*S
#define N_DIM 2048
#define K_DIM 2048

typedef __bf16 bf16x8_t __attribute__((ext_vector_type(8)));
typedef float f32x4_t __attribute__((ext_vector_type(4)));
typedef float f32x16_t __attribute__((ext_vector_type(16)));

// ---------------- threefry2x32, JAX partitionable path, key=(0,1) -------------
// bits(j) = o0^o1 of threefry2x32(key=(0,1), ctr=(0, j)); keep iff bits < 0xC0000000.
// Verified: absmax 0.0625 -> mask exact.
__device__ __forceinline__ unsigned tf_rotl(unsigned x, int r) {
  return (x << r) | (x >> (32 - r));
}
__device__ __forceinline__ unsigned threefry_mask_bits(unsigned ctr) {
  unsigned x0 = 0u, x1 = ctr;
  const unsigned ks0 = 0u, ks1 = 1u, ks2 = 0x1BD11BDBu;
  x0 += ks0; x1 += ks1;
#define TFR(r) { x0 += x1; x1 = tf_rotl(x1, (r)); x1 ^= x0; }
  TFR(13) TFR(15) TFR(26) TFR(6)
  x0 += ks1; x1 += ks2 + 1u;
  TFR(17) TFR(29) TFR(16) TFR(24)
  x0 += ks2; x1 += ks0 + 2u;
  TFR(13) TFR(15) TFR(26) TFR(6)
  x0 += ks0; x1 += ks1 + 3u;
  TFR(17) TFR(29) TFR(16) TFR(24)
  x0 += ks1; x1 += ks2 + 4u;
  TFR(13) TFR(15) TFR(26) TFR(6)
  x0 += ks2; x1 += ks0 + 5u;
#undef TFR
  return x0 ^ x1;
}

// ---------------- async global->LDS, 16B per lane -----------------------------
__device__ __forceinline__ void gload_lds16(const __hip_bfloat16* g, unsigned short* l) {
  __builtin_amdgcn_global_load_lds(
      (const __attribute__((address_space(1))) unsigned int*)g,
      (__attribute__((address_space(3))) unsigned int*)l,
      16, 0, 0);
}

// ---------------- merged prep: LN (blocks 0..8191) + W transpose (8192..10239)
// Round-9 post-mortem: non-GEMM time is a constant ~100us across all rounds
// vs ~25-30us ideal traffic. Culprit: the 32x32 fp32 transpose tiles read only
// 128B per 8KB row stride (DRAM page efficiency ~10-20%) and write 64B
// segments. Fix: 64x64 tiles -> 256B reads / 128B writes per row segment,
// 2048 blocks (was 8192), consecutive blocks sweep bx (same source rows ->
// L2 reuse). LDS 64x65 fp32 (padded, conflict-free), 16.6KB.
__global__ __launch_bounds__(256) void prep_kernel(
    const float* __restrict__ X,  __hip_bfloat16* __restrict__ Xn,
    const float* __restrict__ W1, const float* __restrict__ W2,
    __hip_bfloat16* __restrict__ W1t, __hip_bfloat16* __restrict__ W2t) {
  const int bid = blockIdx.x;
  if (bid < M_DIM) {
    // ---- LayerNorm row (no affine) -> bf16
    const int row = bid;
    const float4* xv = (const float4*)(X + (size_t)row * K_DIM);
    float4 v0 = xv[threadIdx.x];
    float4 v1 = xv[threadIdx.x + 256];
    float s  = v0.x + v0.y + v0.z + v0.w + v1.x + v1.y + v1.z + v1.w;
    float ss = v0.x*v0.x + v0.y*v0.y + v0.z*v0.z + v0.w*v0.w
             + v1.x*v1.x + v1.y*v1.y + v1.z*v1.z + v1.w*v1.w;
#pragma unroll
    for (int off = 32; off > 0; off >>= 1) {
      s  += __shfl_xor(s, off);
      ss += __shfl_xor(ss, off);
    }
    __shared__ float rs[4], rss[4];
    const int wave = threadIdx.x >> 6;
    if ((threadIdx.x & 63) == 0) { rs[wave] = s; rss[wave] = ss; }
    __syncthreads();
    float S  = rs[0] + rs[1] + rs[2] + rs[3];
    float SS = rss[0] + rss[1] + rss[2] + rss[3];
    float mean = S * (1.0f / 2048.0f);
    float var  = SS * (1.0f / 2048.0f) - mean * mean;
    float rstd = 1.0f / sqrtf(var + 1e-6f);
    float vv[8] = {v0.x, v0.y, v0.z, v0.w, v1.x, v1.y, v1.z, v1.w};
    unsigned short o[8];
#pragma unroll
    for (int i = 0; i < 8; i++) {
      __hip_bfloat16 b = __float2bfloat16((vv[i] - mean) * rstd);
      o[i] = *(unsigned short*)&b;
    }
    ushort4* dst = (ushort4*)(Xn + (size_t)row * K_DIM);
    dst[threadIdx.x]       = make_ushort4(o[0], o[1], o[2], o[3]);
    dst[threadIdx.x + 256] = make_ushort4(o[4], o[5], o[6], o[7]);
  } else {
    // ---- W [K][N] fp32 -> Wt [N][K] bf16, 64x64 tile (256B read / 128B write)
    const int t = bid - M_DIM;          // 0..2047
    const int z  = t >> 10;             // 0: W1, 1: W2  (1024 tiles each)
    const int r  = t & 1023;
    const int bx = r & 31;              // N-block (fastest -> row reuse in L2)
    const int by = r >> 5;              // K-block
    const int tx = threadIdx.x & 63;
    const int ty = threadIdx.x >> 6;    // 0..3
    __shared__ float tile[64][65];
    const float* src = z ? W2 : W1;
    __hip_bfloat16* dst = z ? W2t : W1t;
#pragma unroll
    for (int i = 0; i < 64; i += 4)
      tile[ty + i][tx] = src[(size_t)(by * 64 + ty + i) * N_DIM + bx * 64 + tx];
    __syncthreads();
#pragma unroll
    for (int i = 0; i < 64; i += 4)
      dst[(size_t)(bx * 64 + ty + i) * K_DIM + by * 64 + tx] =
          __float2bfloat16(tile[tx][ty + i]);
  }
}

// ---------------- 128x128 MFMA GEMM, BK=64 dbuf, counted vmcnt, 32x32x16 ------
// Round-8 kernel verbatim (best measured: 104.9us/GEMM, passed, absmax 0.0625).
// BK=64 dbuf, counted VMW(8), 2 blocks/CU, 256 threads / 4 waves (2Mx2N),
// 32x32x16 MFMA, acc = 2x2 x f32x16 = 64 AGPR.
// Pipeline per tile t (buf=t&1): COMPUTE(buf); s_barrier; STAGE(buf, t+2);
// vmcnt(8) [only the just-issued stage may remain -> tile t+1 fully landed];
// s_barrier. Drain vmcnt(0) only at tile 30; tile 31 computes only.
// C/D layout (m74/m101-verified): col = lane&31, row = (reg&3) + 8*(reg>>2)
// + 4*(lane>>5). EPI=0: H=relu(A@B)->bf16. EPI=1: out=Xn+dropout/0.75.
template <int EPI>
__global__ __launch_bounds__(256) void gemm128(
    const __hip_bfloat16* __restrict__ A,
    const __hip_bfloat16* __restrict__ Bt,
    const __hip_bfloat16* __restrict__ Xn,   // EPI=1 residual
    __hip_bfloat16* __restrict__ Hout,       // EPI=0 output
    float* __restrict__ Fout) {              // EPI=1 output
  __shared__ unsigned short As[2][128 * 64];  // 32 KB
  __shared__ unsigned short Bs[2][128 * 64];  // 32 KB
  const int tid  = threadIdx.x;
  const int lane = tid & 63;
  const int wave = tid >> 6;
  const int wm = wave >> 1, wn = wave & 1;
  // grid: x walks M (fastest) -> consecutive blocks share the B panel in L2.
  const int mBase = blockIdx.x * 128;
  const int nBase = blockIdx.y * 128;

  f32x16_t acc[2][2];
#pragma unroll
  for (int i = 0; i < 2; i++)
#pragma unroll
    for (int j = 0; j < 2; j++)
#pragma unroll
      for (int e = 0; e < 16; e++) acc[i][j][e] = 0.0f;

  // ---- staging: 16 KB per matrix per stage = 16 chunks of 1 KB (8 rows x 128B).
  // wave w loads chunks {w, w+4, w+8, w+12} of A and of B (8 gloads/stage).
  // lane l covers row 8*ca + (l>>3), source k-chunk (l&7)^((l>>3)&7) (swizzle).
  const int rowIn  = lane >> 3;                       // 0..7 within chunk
  const int csrc   = ((lane & 7) ^ (rowIn & 7)) << 3; // swizzled src k-elem offset
  const __hip_bfloat16* aSrc[4];
  const __hip_bfloat16* bSrc[4];
  int sDst[4];
#pragma unroll
  for (int j = 0; j < 4; j++) {
    const int ca = wave + 4 * j;                      // chunk index 0..15
    aSrc[j] = A  + (size_t)(mBase + 8 * ca + rowIn) * K_DIM + csrc;
    bSrc[j] = Bt + (size_t)(nBase + 8 * ca + rowIn) * K_DIM + csrc;
    sDst[j] = ca * 512;                               // shorts: 1KB per chunk
  }

  // ---- fragment read addresses for 32x32x16 (slot = chunk ^ (row&7))
  const int r32 = lane & 31;            // row/col within 32-tile
  const int kg  = lane >> 5;            // 0/1: which 8-elem k-group
  const int sw  = r32 & 7;              // row&7 (wm*64, mt*32 are 0 mod 8)
  const int rowA0 = (wm * 64 +      r32) * 64;   // mt=0, shorts
  const int rowA1 = (wm * 64 + 32 + r32) * 64;   // mt=1
  const int rowB0 = (wn * 64 +      r32) * 64;   // nt=0
  const int rowB1 = (wn * 64 + 32 + r32) * 64;   // nt=1

#define STAGE(buf, k0)                                        \
  {                                                           \
    _Pragma("unroll")                                         \
    for (int j = 0; j < 4; j++) {                             \
      gload_lds16(aSrc[j] + (k0), &As[buf][sDst[j]]);         \
      gload_lds16(bSrc[j] + (k0), &Bs[buf][sDst[j]]);         \
    }                                                         \
  }

  // per k-slice ks (K=16): chunk = 2*ks + kg, slot = chunk^sw, shorts <<3
#define COMPUTE(buf)                                                            \
  {                                                                             \
    _Pragma("unroll")                                                           \
    for (int ks = 0; ks < 4; ks++) {                                            \
      const int ck = (((ks << 1) | kg) ^ sw) << 3;                              \
      bf16x8_t a0 = *(const bf16x8_t*)(&As[buf][rowA0 + ck]);                   \
      bf16x8_t a1 = *(const bf16x8_t*)(&As[buf][rowA1 + ck]);                   \
      bf16x8_t b0 = *(const bf16x8_t*)(&Bs[buf][rowB0 + ck]);                   \
      bf16x8_t b1 = *(const bf16x8_t*)(&Bs[buf][rowB1 + ck]);                   \
      acc[0][0] = __builtin_amdgcn_mfma_f32_32x32x16_bf16(a0, b0, acc[0][0], 0, 0, 0); \
      acc[0][1] = __builtin_amdgcn_mfma_f32_32x32x16_bf16(a0, b1, acc[0][1], 0, 0, 0); \
      acc[1][0] = __builtin_amdgcn_mfma_f32_32x32x16_bf16(a1, b0, acc[1][0], 0, 0, 0); \
      acc[1][1] = __builtin_amdgcn_mfma_f32_32x32x16_bf16(a1, b1, acc[1][1], 0, 0, 0); \
    }                                                                           \
  }

#define BAR() __builtin_amdgcn_s_barrier()
#define VMW(n)  asm volatile("s_waitcnt vmcnt(" #n ")" ::: "memory")

  // TSTEP(BUF, STG, KNEXT, VMODE): one K-64 tile on buffer BUF (literal).
  // STG: stage tile t+2 at offset KNEXT into BUF. VMODE 0 = VMW(8) counted,
  // 1 = VMW(0) drain (tile 30), 2 = none (tile 31).
#define TSTEP(BUF, STG, KNEXT, VMODE)                                    \
  {                                                                      \
    COMPUTE(BUF)                                                         \
    BAR();                        /* all waves done reading BUF */       \
    if (STG) { STAGE(BUF, KNEXT) }                                       \
    if ((VMODE) == 0) { VMW(8); } else if ((VMODE) == 1) { VMW(0); }     \
    if ((VMODE) != 2) { BAR(); }  /* next buffer published */            \
  }

  // ---- prologue: tiles 0 and 1 staged; VMW(8) -> tile0's 8 gloads landed.
  STAGE(0, 0)
  STAGE(1, 64)
  VMW(8);
  BAR();

  // 32 K-tiles. Pairs (t, t+1) with literal buffers; tile t stages t+2.
  for (int k0 = 0; k0 < 1920; k0 += 128) {
    TSTEP(0, 1, k0 + 128, 0)
    TSTEP(1, 1, k0 + 192, 0)
  }
  TSTEP(0, 0, 0, 1)
  TSTEP(1, 0, 0, 2)

#undef TSTEP
#undef STAGE
#undef COMPUTE
#undef BAR
#undef VMW

  // epilogue: 32x32 C/D layout: col = r32, row = (r&3) + 8*(r>>2) + 4*kg
  const int mRow = mBase + wm * 64;
  const int nCol = nBase + wn * 64;
#pragma unroll
  for (int mt = 0; mt < 2; mt++) {
#pragma unroll
    for (int nt = 0; nt < 2; nt++) {
      const int col = nCol + nt * 32 + r32;
#pragma unroll
      for (int r = 0; r < 16; r++) {
        const int row = mRow + mt * 32 + (r & 3) + ((r >> 2) << 3) + (kg << 2);
        float v = acc[mt][nt][r];
        size_t j = (size_t)row * N_DIM + col;
        if (EPI == 0) {
          Hout[j] = __float2bfloat16(fmaxf(v, 0.0f));
        } else {
          unsigned bits = threefry_mask_bits((unsigned)j);
          float y  = (bits < 0xC0000000u) ? v * (1.0f / 0.75f) : 0.0f;
          Fout[j]  = __bfloat162float(Xn[j]) + y;
        }
      }
    }
  }
}

extern "C" void kernel_launch(void* const* d_in, const int* in_sizes, int n_in,
                              void* d_out, int out_size, void* d_ws, size_t ws_size,
                              hipStream_t stream) {
  (void)in_sizes; (void)n_in; (void)out_size; (void)ws_size;
  const float* X  = (const float*)d_in[0];
  const float* W1 = (const float*)d_in[1];
  const float* W2 = (const float*)d_in[2];
  float* out = (float*)d_out;

  unsigned char* ws = (unsigned char*)d_ws;
  __hip_bfloat16* Xn  = (__hip_bfloat16*)(ws);                       // 32 MB
  __hip_bfloat16* H   = (__hip_bfloat16*)(ws + ((size_t)32 << 20));  // 32 MB
  __hip_bfloat16* W1t = (__hip_bfloat16*)(ws + ((size_t)64 << 20));  //  8 MB
  __hip_bfloat16* W2t = (__hip_bfloat16*)(ws + ((size_t)72 << 20));  //  8 MB

  prep_kernel<<<dim3(M_DIM + 2048, 1, 1), 256, 0, stream>>>(X, Xn, W1, W2, W1t, W2t);
  gemm128<0><<<dim3(M_DIM / 128, N_DIM / 128), 256, 0, stream>>>(Xn, W1t, nullptr, H, nullptr);
  gemm128<1><<<dim3(M_DIM / 128, N_DIM / 128), 256, 0, stream>>>(H, W2t, Xn, nullptr, out);
}